// Round 1
// baseline (8036.514 us; speedup 1.0000x reference)
//
#include <hip/hip_runtime.h>
#include <stdint.h>

#define NPTS   32768
#define NBATCH 8
#define NFPS   512
#define NGRP   32
#define BIGF   1e10f
#define R2F    0.04f
#define CAP    2048

// ---------------------------------------------------------------------------
// FPS: one block per batch. x,y,dist live in VGPRs (32 pts/thread * 1024 thr).
// z is streamed each iteration, either from a pre-transposed contiguous
// scratch array (USE_ZT, coalesced 4B stride) or strided from xyz.
// Distance math matches the reference bit-exactly: no FMA contraction,
// sum order (dx^2 + dy^2) + dz^2, min-accumulate, argmax = first max index.
// ---------------------------------------------------------------------------
template <bool USE_ZT>
__global__ __launch_bounds__(1024) void fps_kernel(
    const float* __restrict__ xyz,
    const int* __restrict__ finit,
    int* __restrict__ cidx,        // [NBATCH][NFPS]
    float* __restrict__ zt)        // [NBATCH][NPTS] scratch (may be null)
{
#pragma clang fp contract(off)
    const int b = blockIdx.x;
    const int t = threadIdx.x;
    const float* __restrict__ base = xyz + (size_t)b * (NPTS * 3);
    float* __restrict__ ztb = USE_ZT ? (zt + (size_t)b * NPTS) : nullptr;

    __shared__ float redF[16];
    __shared__ int   redI[16];
    __shared__ float mbox;
    __shared__ int   ibox;

    float xr[32], yr[32], dist[32];
#pragma unroll
    for (int k = 0; k < 32; ++k) {
        const int p = k * 1024 + t;
        xr[k]   = base[3 * p + 0];
        yr[k]   = base[3 * p + 1];
        dist[k] = BIGF;
        if (USE_ZT) ztb[p] = base[3 * p + 2];
    }
    int far = finit[b];
    __syncthreads();   // zt visible to block; also orders LDS init

    const int wid  = t >> 6;
    const int lane = t & 63;

    for (int it = 0; it < NFPS; ++it) {
        if (t == 0) cidx[b * NFPS + it] = far;   // record BEFORE update (scan semantics)
        const float cx = base[3 * far + 0];
        const float cy = base[3 * far + 1];
        const float cz = base[3 * far + 2];

        float vmax = -1.0f;
#pragma unroll
        for (int k = 0; k < 32; ++k) {
            const int p = k * 1024 + t;
            const float zv = USE_ZT ? ztb[p] : base[3 * p + 2];
            float dx = xr[k] - cx;
            float dy = yr[k] - cy;
            float dz = zv    - cz;
            float d  = dx * dx + dy * dy;
            d = d + dz * dz;
            float dk = fminf(dist[k], d);
            dist[k] = dk;
            vmax = fmaxf(vmax, dk);
        }

        // ---- block max reduce ----
        float v = vmax;
#pragma unroll
        for (int off = 32; off >= 1; off >>= 1) v = fmaxf(v, __shfl_xor(v, off, 64));
        if (lane == 0) redF[wid] = v;
        __syncthreads();
        if (t < 64) {
            float w = (lane < 16) ? redF[lane] : -1.0f;
#pragma unroll
            for (int off = 8; off >= 1; off >>= 1) w = fmaxf(w, __shfl_xor(w, off, 64));
            if (lane == 0) mbox = w;
        }
        __syncthreads();
        const float M = mbox;

        // ---- rescan: smallest global index with dist == M (first-max) ----
        int cand = 0x7fffffff;
#pragma unroll
        for (int k = 0; k < 32; ++k) {
            const int p = k * 1024 + t;
            cand = min(cand, (dist[k] == M) ? p : 0x7fffffff);
        }
#pragma unroll
        for (int off = 32; off >= 1; off >>= 1) cand = min(cand, __shfl_xor(cand, off, 64));
        if (lane == 0) redI[wid] = cand;
        __syncthreads();
        if (t < 64) {
            int u = (lane < 16) ? redI[lane] : 0x7fffffff;
#pragma unroll
            for (int off = 8; off >= 1; off >>= 1) u = min(u, __shfl_xor(u, off, 64));
            if (lane == 0) ibox = u;
        }
        __syncthreads();
        far = ibox;
    }
}

// ---------------------------------------------------------------------------
// Ball query + grouping: one block per (b, s) centroid.
// Collect in-radius keys (distbits<<32 | idx) -> LDS, rank-select the 32
// smallest (== stable argsort take-32). Slots beyond the in-radius count are
// filled with the lowest-index out-of-radius points, which provably lie in
// indices 0..62 -> one 64-lane ballot mask.
// ---------------------------------------------------------------------------
__global__ __launch_bounds__(256) void ballq_kernel(
    const float* __restrict__ xyz,
    const int* __restrict__ cidx,
    float* __restrict__ out0,      // [B][S][33][3]
    float* __restrict__ out1)      // [B][S][3]
{
#pragma clang fp contract(off)
    const int blk = blockIdx.x;          // b*NFPS + s
    const int b   = blk >> 9;
    const int t   = threadIdx.x;
    const float* __restrict__ base = xyz + (size_t)b * (NPTS * 3);

    __shared__ unsigned long long list[CAP];
    __shared__ int scnt;
    __shared__ unsigned long long mask0;
    __shared__ int selIdx[32];

    if (t == 0) scnt = 0;
    __syncthreads();

    const int ci = cidx[blk];
    const float cx = base[3 * ci + 0];
    const float cy = base[3 * ci + 1];
    const float cz = base[3 * ci + 2];

    // in-ball mask for the first 64 indices (fill candidates)
    if (t < 64) {
        float dx = base[3 * t + 0] - cx;
        float dy = base[3 * t + 1] - cy;
        float dz = base[3 * t + 2] - cz;
        float d  = dx * dx + dy * dy;
        d = d + dz * dz;
        unsigned long long mk = __ballot(d <= R2F);
        if (t == 0) mask0 = mk;
    }

    // scan all points, append in-radius candidates
#pragma unroll 4
    for (int k = 0; k < NPTS / 256; ++k) {
        const int p = k * 256 + t;
        float dx = base[3 * p + 0] - cx;
        float dy = base[3 * p + 1] - cy;
        float dz = base[3 * p + 2] - cz;
        float d  = dx * dx + dy * dy;
        d = d + dz * dz;
        if (d <= R2F) {
            int pos = atomicAdd(&scnt, 1);
            if (pos < CAP)
                list[pos] = (((unsigned long long)__float_as_uint(d)) << 32)
                            | (unsigned)p;
        }
    }
    __syncthreads();

    const int m = min(scnt, CAP);
    const int K = min(m, NGRP);

    // rank-based selection: key's rank == #smaller keys (keys unique via idx)
    for (int j = t; j < m; j += 256) {
        const unsigned long long kj = list[j];
        int rank = 0;
        for (int i = 0; i < m; ++i) rank += (list[i] < kj) ? 1 : 0;
        if (rank < NGRP) selIdx[rank] = (int)(kj & 0xffffffffu);
    }
    __syncthreads();

    if (t < 33) {
        const size_t o0 = (size_t)blk * 33 * 3;
        if (t == 32) {
            out0[o0 + 0] = cx; out0[o0 + 1] = cy; out0[o0 + 2] = cz;
            const size_t o1 = (size_t)blk * 3;
            out1[o1 + 0] = cx; out1[o1 + 1] = cy; out1[o1 + 2] = cz;
        } else {
            int idx;
            if (t < K) {
                idx = selIdx[t];
            } else {
                // (t-K+1)-th zero bit of mask0 = next smallest out-of-radius index
                unsigned long long zeros = ~mask0;
                const int need = t - K;
                for (int q = 0; q < need; ++q) zeros &= zeros - 1;
                idx = __builtin_ctzll(zeros);
            }
            const float px = base[3 * idx + 0];
            const float py = base[3 * idx + 1];
            const float pz = base[3 * idx + 2];
            out0[o0 + (size_t)(1 + t) * 3 + 0] = px - cx;
            out0[o0 + (size_t)(1 + t) * 3 + 1] = py - cy;
            out0[o0 + (size_t)(1 + t) * 3 + 2] = pz - cz;
        }
    }
}

extern "C" void kernel_launch(void* const* d_in, const int* in_sizes, int n_in,
                              void* d_out, int out_size, void* d_ws, size_t ws_size,
                              hipStream_t stream) {
    const float* xyz   = (const float*)d_in[0];
    const int*   finit = (const int*)d_in[1];
    float* out0 = (float*)d_out;
    float* out1 = out0 + (size_t)NBATCH * NFPS * 33 * 3;

    int*   cidx = (int*)d_ws;
    float* zt   = (float*)((char*)d_ws + (size_t)NBATCH * NFPS * sizeof(int));
    const size_t need = (size_t)NBATCH * NFPS * sizeof(int)
                      + (size_t)NBATCH * NPTS * sizeof(float);

    if (ws_size >= need) {
        fps_kernel<true><<<NBATCH, 1024, 0, stream>>>(xyz, finit, cidx, zt);
    } else {
        fps_kernel<false><<<NBATCH, 1024, 0, stream>>>(xyz, finit, cidx, nullptr);
    }
    ballq_kernel<<<NBATCH * NFPS, 256, 0, stream>>>(xyz, cidx, out0, out1);
}

// Round 2
// 7586.085 us; speedup vs baseline: 1.0594x; 1.0594x over previous
//
#include <hip/hip_runtime.h>
#include <stdint.h>

#define NPTS   32768
#define NBATCH 8
#define NFPS   512
#define NGRP   32
#define BIGF   1e10f
#define R2F    0.04f
#define CAP    2048

__device__ __forceinline__ unsigned long long shfl_xor_u64(unsigned long long v, int off) {
    unsigned lo = (unsigned)v, hi = (unsigned)(v >> 32);
    lo = __shfl_xor(lo, off, 64);
    hi = __shfl_xor(hi, off, 64);
    return ((unsigned long long)hi << 32) | lo;
}

// ---------------------------------------------------------------------------
// FPS: one block per batch, 1024 threads, 32 points/thread (p = t*32 + k).
// x,y,dist in VGPRs (96 regs) -- __launch_bounds__(1024,4) raises the VGPR
// cap to 128 (default occupancy target capped at 64 and spilled everything:
// R1 showed VGPR_Count=64 and 10x slowdown from scratch round-trips).
// z streams from contiguous scratch (self-owned entries, float4 loads).
// Argmax fused into main loop: strict '>' keeps first occurrence per thread;
// block reduce on u64 key (distbits<<32 | ~idx) -> max dist, ties -> min idx.
// Distance math matches reference bit-exactly: contract off, (dx2+dy2)+dz2.
// ---------------------------------------------------------------------------
template <bool USE_ZT>
__global__ __launch_bounds__(1024, 4) void fps_kernel(
    const float* __restrict__ xyz,
    const int* __restrict__ finit,
    int* __restrict__ cidx,        // [NBATCH][NFPS]
    float* __restrict__ zt)        // [NBATCH][NPTS] scratch (may be null)
{
#pragma clang fp contract(off)
    const int b = blockIdx.x;
    const int t = threadIdx.x;
    const float* __restrict__ base = xyz + (size_t)b * (NPTS * 3);
    float* __restrict__ ztb = USE_ZT ? (zt + (size_t)b * NPTS) : nullptr;

    __shared__ unsigned long long redK[16];
    __shared__ unsigned long long kbox;

    float xr[32], yr[32], dist[32];
#pragma unroll
    for (int k = 0; k < 32; ++k) {
        const int p = t * 32 + k;
        xr[k]   = base[3 * p + 0];
        yr[k]   = base[3 * p + 1];
        dist[k] = BIGF;
        if (USE_ZT) ztb[p] = base[3 * p + 2];
    }
    int far = finit[b];

    const int wid  = t >> 6;
    const int lane = t & 63;

    for (int it = 0; it < NFPS; ++it) {
        if (t == 0) cidx[b * NFPS + it] = far;   // record BEFORE update (scan semantics)
        const float cx = base[3 * far + 0];
        const float cy = base[3 * far + 1];
        const float cz = base[3 * far + 2];

        float vmax = -1.0f;
        int   amax = 0;
        if (USE_ZT) {
            const float4* __restrict__ z4 =
                reinterpret_cast<const float4*>(ztb + t * 32);
#pragma unroll
            for (int j = 0; j < 8; ++j) {
                const float4 zv = z4[j];
                const float zq[4] = {zv.x, zv.y, zv.z, zv.w};
#pragma unroll
                for (int q = 0; q < 4; ++q) {
                    const int k = j * 4 + q;
                    const int p = t * 32 + k;
                    float dx = xr[k] - cx;
                    float dy = yr[k] - cy;
                    float dz = zq[q] - cz;
                    float d  = dx * dx + dy * dy;
                    d = d + dz * dz;
                    float dk = fminf(dist[k], d);
                    dist[k] = dk;
                    if (dk > vmax) { vmax = dk; amax = p; }
                }
            }
        } else {
#pragma unroll
            for (int k = 0; k < 32; ++k) {
                const int p = t * 32 + k;
                float dx = xr[k] - cx;
                float dy = yr[k] - cy;
                float dz = base[3 * p + 2] - cz;
                float d  = dx * dx + dy * dy;
                d = d + dz * dz;
                float dk = fminf(dist[k], d);
                dist[k] = dk;
                if (dk > vmax) { vmax = dk; amax = p; }
            }
        }

        // u64 key: high=distbits (>=0 so bit order == float order), low=~idx
        unsigned long long key =
            ((unsigned long long)__float_as_uint(vmax) << 32)
            | (unsigned)(0xFFFFFFFFu - (unsigned)amax);
#pragma unroll
        for (int off = 32; off >= 1; off >>= 1) {
            unsigned long long o = shfl_xor_u64(key, off);
            key = (o > key) ? o : key;
        }
        if (lane == 0) redK[wid] = key;
        __syncthreads();
        if (t < 64) {
            unsigned long long w = (lane < 16) ? redK[lane] : 0ull;
#pragma unroll
            for (int off = 8; off >= 1; off >>= 1) {
                unsigned long long o = shfl_xor_u64(w, off);
                w = (o > w) ? o : w;
            }
            if (lane == 0) kbox = w;
        }
        __syncthreads();
        far = (int)(0xFFFFFFFFu - (unsigned)(kbox & 0xFFFFFFFFull));
    }
}

// ---------------------------------------------------------------------------
// Ball query + grouping: one block per (b, s) centroid. (unchanged from R1)
// ---------------------------------------------------------------------------
__global__ __launch_bounds__(256) void ballq_kernel(
    const float* __restrict__ xyz,
    const int* __restrict__ cidx,
    float* __restrict__ out0,      // [B][S][33][3]
    float* __restrict__ out1)      // [B][S][3]
{
#pragma clang fp contract(off)
    const int blk = blockIdx.x;          // b*NFPS + s
    const int b   = blk >> 9;
    const int t   = threadIdx.x;
    const float* __restrict__ base = xyz + (size_t)b * (NPTS * 3);

    __shared__ unsigned long long list[CAP];
    __shared__ int scnt;
    __shared__ unsigned long long mask0;
    __shared__ int selIdx[32];

    if (t == 0) scnt = 0;
    __syncthreads();

    const int ci = cidx[blk];
    const float cx = base[3 * ci + 0];
    const float cy = base[3 * ci + 1];
    const float cz = base[3 * ci + 2];

    // in-ball mask for the first 64 indices (fill candidates)
    if (t < 64) {
        float dx = base[3 * t + 0] - cx;
        float dy = base[3 * t + 1] - cy;
        float dz = base[3 * t + 2] - cz;
        float d  = dx * dx + dy * dy;
        d = d + dz * dz;
        unsigned long long mk = __ballot(d <= R2F);
        if (t == 0) mask0 = mk;
    }

    // scan all points, append in-radius candidates
#pragma unroll 4
    for (int k = 0; k < NPTS / 256; ++k) {
        const int p = k * 256 + t;
        float dx = base[3 * p + 0] - cx;
        float dy = base[3 * p + 1] - cy;
        float dz = base[3 * p + 2] - cz;
        float d  = dx * dx + dy * dy;
        d = d + dz * dz;
        if (d <= R2F) {
            int pos = atomicAdd(&scnt, 1);
            if (pos < CAP)
                list[pos] = (((unsigned long long)__float_as_uint(d)) << 32)
                            | (unsigned)p;
        }
    }
    __syncthreads();

    const int m = min(scnt, CAP);
    const int K = min(m, NGRP);

    // rank-based selection: key's rank == #smaller keys (keys unique via idx)
    for (int j = t; j < m; j += 256) {
        const unsigned long long kj = list[j];
        int rank = 0;
        for (int i = 0; i < m; ++i) rank += (list[i] < kj) ? 1 : 0;
        if (rank < NGRP) selIdx[rank] = (int)(kj & 0xffffffffu);
    }
    __syncthreads();

    if (t < 33) {
        const size_t o0 = (size_t)blk * 33 * 3;
        if (t == 32) {
            out0[o0 + 0] = cx; out0[o0 + 1] = cy; out0[o0 + 2] = cz;
            const size_t o1 = (size_t)blk * 3;
            out1[o1 + 0] = cx; out1[o1 + 1] = cy; out1[o1 + 2] = cz;
        } else {
            int idx;
            if (t < K) {
                idx = selIdx[t];
            } else {
                // (t-K+1)-th zero bit of mask0 = next smallest out-of-radius index
                unsigned long long zeros = ~mask0;
                const int need = t - K;
                for (int q = 0; q < need; ++q) zeros &= zeros - 1;
                idx = __builtin_ctzll(zeros);
            }
            const float px = base[3 * idx + 0];
            const float py = base[3 * idx + 1];
            const float pz = base[3 * idx + 2];
            out0[o0 + (size_t)(1 + t) * 3 + 0] = px - cx;
            out0[o0 + (size_t)(1 + t) * 3 + 1] = py - cy;
            out0[o0 + (size_t)(1 + t) * 3 + 2] = pz - cz;
        }
    }
}

extern "C" void kernel_launch(void* const* d_in, const int* in_sizes, int n_in,
                              void* d_out, int out_size, void* d_ws, size_t ws_size,
                              hipStream_t stream) {
    const float* xyz   = (const float*)d_in[0];
    const int*   finit = (const int*)d_in[1];
    float* out0 = (float*)d_out;
    float* out1 = out0 + (size_t)NBATCH * NFPS * 33 * 3;

    int*   cidx = (int*)d_ws;
    float* zt   = (float*)((char*)d_ws + (size_t)NBATCH * NFPS * sizeof(int));
    const size_t need = (size_t)NBATCH * NFPS * sizeof(int)
                      + (size_t)NBATCH * NPTS * sizeof(float);

    if (ws_size >= need) {
        fps_kernel<true><<<NBATCH, 1024, 0, stream>>>(xyz, finit, cidx, zt);
    } else {
        fps_kernel<false><<<NBATCH, 1024, 0, stream>>>(xyz, finit, cidx, nullptr);
    }
    ballq_kernel<<<NBATCH * NFPS, 256, 0, stream>>>(xyz, cidx, out0, out1);
}

// Round 3
// 7397.659 us; speedup vs baseline: 1.0864x; 1.0255x over previous
//
#include <hip/hip_runtime.h>
#include <stdint.h>

#define NPTS   32768
#define NBATCH 8
#define NFPS   512
#define NGRP   32
#define BIGF   1e10f
#define R2F    0.04f
#define CAP    2048

__device__ __forceinline__ unsigned long long shfl_xor_u64(unsigned long long v, int off) {
    unsigned lo = (unsigned)v, hi = (unsigned)(v >> 32);
    lo = __shfl_xor(lo, off, 64);
    hi = __shfl_xor(hi, off, 64);
    return ((unsigned long long)hi << 32) | lo;
}

// ---------------------------------------------------------------------------
// FPS: one block per batch, 1024 threads, 32 points/thread (p = t*32 + k).
// x,y,dist in VGPRs (96 regs). KEY FIX vs R2: amdgpu_waves_per_eu(4,4) pins
// the allocator's occupancy TARGET (not just the min) to 4 waves/EU -> 128
// VGPR budget. R1/R2 showed VGPR_Count=64: launch_bounds only raises the
// min, the allocator still targeted 8 waves/EU and spilled all arrays to
// scratch (WRITE_SIZE 4.1MB of scratch leak, 20% VALUBusy on active CUs).
// z streams from contiguous scratch (self-owned entries, float4 loads).
// Argmax fused: strict '>' keeps first occurrence per thread; reduce on u64
// key (distbits<<32 | ~idx) -> max dist, ties -> min idx. Single barrier per
// iteration via double-buffered redK. Distance math bit-exact vs reference:
// contract off, (dx^2+dy^2)+dz^2, fminf accumulate.
// ---------------------------------------------------------------------------
template <bool USE_ZT>
__global__
__attribute__((amdgpu_flat_work_group_size(1024, 1024)))
__attribute__((amdgpu_waves_per_eu(4, 4)))
void fps_kernel(
    const float* __restrict__ xyz,
    const int* __restrict__ finit,
    int* __restrict__ cidx,        // [NBATCH][NFPS]
    float* __restrict__ zt)        // [NBATCH][NPTS] scratch (may be null)
{
#pragma clang fp contract(off)
    const int b = blockIdx.x;
    const int t = threadIdx.x;
    const float* __restrict__ base = xyz + (size_t)b * (NPTS * 3);
    float* __restrict__ ztb = USE_ZT ? (zt + (size_t)b * NPTS) : nullptr;

    __shared__ unsigned long long redK[2][16];

    float xr[32], yr[32], dist[32];
#pragma unroll
    for (int k = 0; k < 32; ++k) {
        const int p = t * 32 + k;
        xr[k]   = base[3 * p + 0];
        yr[k]   = base[3 * p + 1];
        dist[k] = BIGF;
        if (USE_ZT) ztb[p] = base[3 * p + 2];   // self-owned entries, no barrier needed
    }
    int far = finit[b];

    const int wid  = t >> 6;
    const int lane = t & 63;
    int parity = 0;

    for (int it = 0; it < NFPS; ++it) {
        if (t == 0) cidx[b * NFPS + it] = far;   // record BEFORE update (scan semantics)
        const float cx = base[3 * far + 0];
        const float cy = base[3 * far + 1];
        const float cz = base[3 * far + 2];

        float vmax = -1.0f;
        int   amax = 0;
        if (USE_ZT) {
            const float4* __restrict__ z4 =
                reinterpret_cast<const float4*>(ztb + t * 32);
#pragma unroll
            for (int j = 0; j < 8; ++j) {
                const float4 zv = z4[j];
                const float zq[4] = {zv.x, zv.y, zv.z, zv.w};
#pragma unroll
                for (int q = 0; q < 4; ++q) {
                    const int k = j * 4 + q;
                    const int p = t * 32 + k;
                    float dx = xr[k] - cx;
                    float dy = yr[k] - cy;
                    float dz = zq[q] - cz;
                    float d  = dx * dx + dy * dy;
                    d = d + dz * dz;
                    float dk = fminf(dist[k], d);
                    dist[k] = dk;
                    if (dk > vmax) { vmax = dk; amax = p; }
                }
            }
        } else {
#pragma unroll
            for (int k = 0; k < 32; ++k) {
                const int p = t * 32 + k;
                float dx = xr[k] - cx;
                float dy = yr[k] - cy;
                float dz = base[3 * p + 2] - cz;
                float d  = dx * dx + dy * dy;
                d = d + dz * dz;
                float dk = fminf(dist[k], d);
                dist[k] = dk;
                if (dk > vmax) { vmax = dk; amax = p; }
            }
        }

        // u64 key: high=distbits (>=0 so bit order == float order), low=~idx
        unsigned long long key =
            ((unsigned long long)__float_as_uint(vmax) << 32)
            | (unsigned)(0xFFFFFFFFu - (unsigned)amax);
#pragma unroll
        for (int off = 32; off >= 1; off >>= 1) {
            unsigned long long o = shfl_xor_u64(key, off);
            key = (o > key) ? o : key;
        }
        if (lane == 0) redK[parity][wid] = key;
        __syncthreads();
        // every thread serially reduces the 16 wave keys (LDS broadcast reads).
        // next iteration's leader-writes go to the OTHER buffer, so no second
        // barrier is required before they happen.
        unsigned long long best = redK[parity][0];
#pragma unroll
        for (int w = 1; w < 16; ++w) {
            unsigned long long o = redK[parity][w];
            best = (o > best) ? o : best;
        }
        far = (int)(0xFFFFFFFFu - (unsigned)(best & 0xFFFFFFFFull));
        parity ^= 1;
    }
}

// ---------------------------------------------------------------------------
// Ball query + grouping: one block per (b, s) centroid. (unchanged from R2)
// ---------------------------------------------------------------------------
__global__ __launch_bounds__(256) void ballq_kernel(
    const float* __restrict__ xyz,
    const int* __restrict__ cidx,
    float* __restrict__ out0,      // [B][S][33][3]
    float* __restrict__ out1)      // [B][S][3]
{
#pragma clang fp contract(off)
    const int blk = blockIdx.x;          // b*NFPS + s
    const int b   = blk >> 9;
    const int t   = threadIdx.x;
    const float* __restrict__ base = xyz + (size_t)b * (NPTS * 3);

    __shared__ unsigned long long list[CAP];
    __shared__ int scnt;
    __shared__ unsigned long long mask0;
    __shared__ int selIdx[32];

    if (t == 0) scnt = 0;
    __syncthreads();

    const int ci = cidx[blk];
    const float cx = base[3 * ci + 0];
    const float cy = base[3 * ci + 1];
    const float cz = base[3 * ci + 2];

    // in-ball mask for the first 64 indices (fill candidates)
    if (t < 64) {
        float dx = base[3 * t + 0] - cx;
        float dy = base[3 * t + 1] - cy;
        float dz = base[3 * t + 2] - cz;
        float d  = dx * dx + dy * dy;
        d = d + dz * dz;
        unsigned long long mk = __ballot(d <= R2F);
        if (t == 0) mask0 = mk;
    }

    // scan all points, append in-radius candidates
#pragma unroll 4
    for (int k = 0; k < NPTS / 256; ++k) {
        const int p = k * 256 + t;
        float dx = base[3 * p + 0] - cx;
        float dy = base[3 * p + 1] - cy;
        float dz = base[3 * p + 2] - cz;
        float d  = dx * dx + dy * dy;
        d = d + dz * dz;
        if (d <= R2F) {
            int pos = atomicAdd(&scnt, 1);
            if (pos < CAP)
                list[pos] = (((unsigned long long)__float_as_uint(d)) << 32)
                            | (unsigned)p;
        }
    }
    __syncthreads();

    const int m = min(scnt, CAP);
    const int K = min(m, NGRP);

    // rank-based selection: key's rank == #smaller keys (keys unique via idx)
    for (int j = t; j < m; j += 256) {
        const unsigned long long kj = list[j];
        int rank = 0;
        for (int i = 0; i < m; ++i) rank += (list[i] < kj) ? 1 : 0;
        if (rank < NGRP) selIdx[rank] = (int)(kj & 0xffffffffu);
    }
    __syncthreads();

    if (t < 33) {
        const size_t o0 = (size_t)blk * 33 * 3;
        if (t == 32) {
            out0[o0 + 0] = cx; out0[o0 + 1] = cy; out0[o0 + 2] = cz;
            const size_t o1 = (size_t)blk * 3;
            out1[o1 + 0] = cx; out1[o1 + 1] = cy; out1[o1 + 2] = cz;
        } else {
            int idx;
            if (t < K) {
                idx = selIdx[t];
            } else {
                // (t-K+1)-th zero bit of mask0 = next smallest out-of-radius index
                unsigned long long zeros = ~mask0;
                const int need = t - K;
                for (int q = 0; q < need; ++q) zeros &= zeros - 1;
                idx = __builtin_ctzll(zeros);
            }
            const float px = base[3 * idx + 0];
            const float py = base[3 * idx + 1];
            const float pz = base[3 * idx + 2];
            out0[o0 + (size_t)(1 + t) * 3 + 0] = px - cx;
            out0[o0 + (size_t)(1 + t) * 3 + 1] = py - cy;
            out0[o0 + (size_t)(1 + t) * 3 + 2] = pz - cz;
        }
    }
}

extern "C" void kernel_launch(void* const* d_in, const int* in_sizes, int n_in,
                              void* d_out, int out_size, void* d_ws, size_t ws_size,
                              hipStream_t stream) {
    const float* xyz   = (const float*)d_in[0];
    const int*   finit = (const int*)d_in[1];
    float* out0 = (float*)d_out;
    float* out1 = out0 + (size_t)NBATCH * NFPS * 33 * 3;

    int*   cidx = (int*)d_ws;
    float* zt   = (float*)((char*)d_ws + (size_t)NBATCH * NFPS * sizeof(int));
    const size_t need = (size_t)NBATCH * NFPS * sizeof(int)
                      + (size_t)NBATCH * NPTS * sizeof(float);

    if (ws_size >= need) {
        fps_kernel<true><<<NBATCH, 1024, 0, stream>>>(xyz, finit, cidx, zt);
    } else {
        fps_kernel<false><<<NBATCH, 1024, 0, stream>>>(xyz, finit, cidx, nullptr);
    }
    ballq_kernel<<<NBATCH * NFPS, 256, 0, stream>>>(xyz, cidx, out0, out1);
}

// Round 4
// 2946.956 us; speedup vs baseline: 2.7271x; 2.5103x over previous
//
#include <hip/hip_runtime.h>
#include <stdint.h>

#define NPTS   32768
#define NBATCH 8
#define NFPS   512
#define NGRP   32
#define BIGF   1e10f
#define R2F    0.04f
#define CAP    2048

__device__ __forceinline__ unsigned long long shfl_xor_u64(unsigned long long v, int off) {
    unsigned lo = (unsigned)v, hi = (unsigned)(v >> 32);
    lo = __shfl_xor(lo, off, 64);
    hi = __shfl_xor(hi, off, 64);
    return ((unsigned long long)hi << 32) | lo;
}

// ---------------------------------------------------------------------------
// FPS: one block per batch, 1024 threads, 32 points/thread (p = t*32 + k).
// R1-R3 LESSON: the compiler pins this 1024-thread kernel to a 64-VGPR
// budget no matter what (__launch_bounds__(1024,4) and waves_per_eu(4,4)
// both failed; WRITE_SIZE showed 3 MB = 8192 thr x 384 B of scratch from
// the xr/yr/dist arrays). So: keep ONLY dist[32] in registers (~57 VGPRs
// total incl. temps) and stream x,y,z every iteration straight from the
// interleaved xyz array as 24 float4 loads/thread (3 float4 = 4 points,
// dense). L2 traffic is line-granular, so interleaved costs the same
// 384 KB/iter as SoA -- no transpose scratch needed at all.
// Argmax fused: strict '>' keeps first occurrence per thread; block reduce
// on u64 key (distbits<<32 | ~idx) -> max dist, ties -> min index. Single
// barrier per iteration via double-buffered redK (proven bit-exact in R3).
// Distance math matches reference exactly: contract off, (dx^2+dy^2)+dz^2,
// fminf accumulate.
// ---------------------------------------------------------------------------
__global__ __launch_bounds__(1024) void fps_kernel(
    const float* __restrict__ xyz,
    const int* __restrict__ finit,
    int* __restrict__ cidx)        // [NBATCH][NFPS]
{
#pragma clang fp contract(off)
    const int b = blockIdx.x;
    const int t = threadIdx.x;
    const float* __restrict__ base = xyz + (size_t)b * (NPTS * 3);
    // thread t owns points p = t*32 .. t*32+31  ->  floats [t*96, t*96+96)
    const float4* __restrict__ b4 =
        reinterpret_cast<const float4*>(base) + (size_t)t * 24;

    __shared__ unsigned long long redK[2][16];

    float dist[32];
#pragma unroll
    for (int k = 0; k < 32; ++k) dist[k] = BIGF;

    int far = finit[b];
    const int wid  = t >> 6;
    const int lane = t & 63;
    int parity = 0;

    for (int it = 0; it < NFPS; ++it) {
        if (t == 0) cidx[b * NFPS + it] = far;   // record BEFORE update (scan semantics)
        const float cx = base[3 * far + 0];
        const float cy = base[3 * far + 1];
        const float cz = base[3 * far + 2];

        float vmax = -1.0f;
        int   amax = 0;

#define PROC(K, PX, PY, PZ)                                   \
        {                                                     \
            const int k_ = (K);                               \
            float dx = (PX) - cx;                             \
            float dy = (PY) - cy;                             \
            float dz = (PZ) - cz;                             \
            float d  = dx * dx + dy * dy;                     \
            d = d + dz * dz;                                  \
            float dk = fminf(dist[k_], d);                    \
            dist[k_] = dk;                                    \
            if (dk > vmax) { vmax = dk; amax = t * 32 + k_; } \
        }

#pragma unroll
        for (int j = 0; j < 8; ++j) {
            const float4 q0 = b4[j * 3 + 0];
            const float4 q1 = b4[j * 3 + 1];
            const float4 q2 = b4[j * 3 + 2];
            PROC(j * 4 + 0, q0.x, q0.y, q0.z);
            PROC(j * 4 + 1, q0.w, q1.x, q1.y);
            PROC(j * 4 + 2, q1.z, q1.w, q2.x);
            PROC(j * 4 + 3, q2.y, q2.z, q2.w);
        }
#undef PROC

        // u64 key: high=distbits (>=0 so bit order == float order), low=~idx
        unsigned long long key =
            ((unsigned long long)__float_as_uint(vmax) << 32)
            | (unsigned)(0xFFFFFFFFu - (unsigned)amax);
#pragma unroll
        for (int off = 32; off >= 1; off >>= 1) {
            unsigned long long o = shfl_xor_u64(key, off);
            key = (o > key) ? o : key;
        }
        if (lane == 0) redK[parity][wid] = key;
        __syncthreads();
        // every thread serially reduces the 16 wave keys (LDS broadcast).
        // next iteration's leader-writes target the OTHER buffer, so no
        // second barrier is needed.
        unsigned long long best = redK[parity][0];
#pragma unroll
        for (int w = 1; w < 16; ++w) {
            unsigned long long o = redK[parity][w];
            best = (o > best) ? o : best;
        }
        far = (int)(0xFFFFFFFFu - (unsigned)(best & 0xFFFFFFFFull));
        parity ^= 1;
    }
}

// ---------------------------------------------------------------------------
// Ball query + grouping: one block per (b, s) centroid. (unchanged from R3)
// ---------------------------------------------------------------------------
__global__ __launch_bounds__(256) void ballq_kernel(
    const float* __restrict__ xyz,
    const int* __restrict__ cidx,
    float* __restrict__ out0,      // [B][S][33][3]
    float* __restrict__ out1)      // [B][S][3]
{
#pragma clang fp contract(off)
    const int blk = blockIdx.x;          // b*NFPS + s
    const int b   = blk >> 9;
    const int t   = threadIdx.x;
    const float* __restrict__ base = xyz + (size_t)b * (NPTS * 3);

    __shared__ unsigned long long list[CAP];
    __shared__ int scnt;
    __shared__ unsigned long long mask0;
    __shared__ int selIdx[32];

    if (t == 0) scnt = 0;
    __syncthreads();

    const int ci = cidx[blk];
    const float cx = base[3 * ci + 0];
    const float cy = base[3 * ci + 1];
    const float cz = base[3 * ci + 2];

    // in-ball mask for the first 64 indices (fill candidates)
    if (t < 64) {
        float dx = base[3 * t + 0] - cx;
        float dy = base[3 * t + 1] - cy;
        float dz = base[3 * t + 2] - cz;
        float d  = dx * dx + dy * dy;
        d = d + dz * dz;
        unsigned long long mk = __ballot(d <= R2F);
        if (t == 0) mask0 = mk;
    }

    // scan all points, append in-radius candidates
#pragma unroll 4
    for (int k = 0; k < NPTS / 256; ++k) {
        const int p = k * 256 + t;
        float dx = base[3 * p + 0] - cx;
        float dy = base[3 * p + 1] - cy;
        float dz = base[3 * p + 2] - cz;
        float d  = dx * dx + dy * dy;
        d = d + dz * dz;
        if (d <= R2F) {
            int pos = atomicAdd(&scnt, 1);
            if (pos < CAP)
                list[pos] = (((unsigned long long)__float_as_uint(d)) << 32)
                            | (unsigned)p;
        }
    }
    __syncthreads();

    const int m = min(scnt, CAP);
    const int K = min(m, NGRP);

    // rank-based selection: key's rank == #smaller keys (keys unique via idx)
    for (int j = t; j < m; j += 256) {
        const unsigned long long kj = list[j];
        int rank = 0;
        for (int i = 0; i < m; ++i) rank += (list[i] < kj) ? 1 : 0;
        if (rank < NGRP) selIdx[rank] = (int)(kj & 0xffffffffu);
    }
    __syncthreads();

    if (t < 33) {
        const size_t o0 = (size_t)blk * 33 * 3;
        if (t == 32) {
            out0[o0 + 0] = cx; out0[o0 + 1] = cy; out0[o0 + 2] = cz;
            const size_t o1 = (size_t)blk * 3;
            out1[o1 + 0] = cx; out1[o1 + 1] = cy; out1[o1 + 2] = cz;
        } else {
            int idx;
            if (t < K) {
                idx = selIdx[t];
            } else {
                // (t-K+1)-th zero bit of mask0 = next smallest out-of-radius index
                unsigned long long zeros = ~mask0;
                const int need = t - K;
                for (int q = 0; q < need; ++q) zeros &= zeros - 1;
                idx = __builtin_ctzll(zeros);
            }
            const float px = base[3 * idx + 0];
            const float py = base[3 * idx + 1];
            const float pz = base[3 * idx + 2];
            out0[o0 + (size_t)(1 + t) * 3 + 0] = px - cx;
            out0[o0 + (size_t)(1 + t) * 3 + 1] = py - cy;
            out0[o0 + (size_t)(1 + t) * 3 + 2] = pz - cz;
        }
    }
}

extern "C" void kernel_launch(void* const* d_in, const int* in_sizes, int n_in,
                              void* d_out, int out_size, void* d_ws, size_t ws_size,
                              hipStream_t stream) {
    const float* xyz   = (const float*)d_in[0];
    const int*   finit = (const int*)d_in[1];
    float* out0 = (float*)d_out;
    float* out1 = out0 + (size_t)NBATCH * NFPS * 33 * 3;

    int* cidx = (int*)d_ws;   // 16 KB; ws proven >= 1 MB in R1-R3

    fps_kernel<<<NBATCH, 1024, 0, stream>>>(xyz, finit, cidx);
    ballq_kernel<<<NBATCH * NFPS, 256, 0, stream>>>(xyz, cidx, out0, out1);
}